// Round 2
// baseline (185.334 us; speedup 1.0000x reference)
//
#include <hip/hip_runtime.h>
#include <hip/hip_bf16.h>
#include <stdint.h>

typedef __attribute__((ext_vector_type(8))) short bf16x8;
typedef __attribute__((ext_vector_type(4))) float f32x4;

#define B_ 32
#define S_ 512
#define I_ 512
#define H_ 1024
#define M_ (B_*S_)      /* 16384 */
#define N_ (3*H_)       /* 3072  */
#define K_ I_           /* 512   */

// ---- helpers: plane load/store in either precision ------------------------
__device__ inline void stv(float* p, size_t i, float v)          { p[i] = v; }
__device__ inline void stv(__hip_bfloat16* p, size_t i, float v) { p[i] = __float2bfloat16(v); }
__device__ inline float ldv(const float* p, size_t i)            { return p[i]; }
__device__ inline float ldv(const __hip_bfloat16* p, size_t i)   { return __bfloat162float(p[i]); }

// ---------------------------------------------------------------------------
// f32 -> bf16 conversion (x and W), 8 elements/thread, 16B stores.
// ---------------------------------------------------------------------------
struct alignas(16) Bf8 { __hip_bfloat16 h[8]; };

__global__ __launch_bounds__(256) void cvt_f32_bf16(
    const float* __restrict__ in, __hip_bfloat16* __restrict__ out, int n8)
{
    const int t = blockIdx.x * 256 + threadIdx.x;
    if (t >= n8) return;
    const float4* p = (const float4*)(in + (size_t)t * 8);
    const float4 a = p[0], b = p[1];
    Bf8 o;
    o.h[0] = __float2bfloat16(a.x); o.h[1] = __float2bfloat16(a.y);
    o.h[2] = __float2bfloat16(a.z); o.h[3] = __float2bfloat16(a.w);
    o.h[4] = __float2bfloat16(b.x); o.h[5] = __float2bfloat16(b.y);
    o.h[6] = __float2bfloat16(b.z); o.h[7] = __float2bfloat16(b.w);
    ((Bf8*)out)[t] = o;
}

// ---------------------------------------------------------------------------
// GEMM + activation epilogue.
//   A  = xb [M_, K_] row-major bf16   (row = b*S + s)
//   Bm = Wb [N_, K_] row-major bf16   (B^T layout, K-contiguous)
//   y = A @ Bm^T + bias ; gate 0 -> tanh -> zbuf ; 1 -> sigmoid -> fbuf ;
//   2 -> sigmoid -> obuf.   Each buf is [M_, H_] of TO.
// 128x128 tile, BK=64, 256 threads = 4 waves in 2x2, mfma_f32_16x16x32_bf16.
// LDS via global_load_lds width 16, XOR swizzle on source cols + read addr
// (linear LDS dest, rule #21: both-sides-or-neither).
// ---------------------------------------------------------------------------
template<typename TO>
__global__ __launch_bounds__(256) void qrnn_gemm_act(
    const __hip_bfloat16* __restrict__ A,
    const __hip_bfloat16* __restrict__ Bm,
    const float* __restrict__ bias,
    TO* __restrict__ zbuf,
    TO* __restrict__ fbuf,
    TO* __restrict__ obuf)
{
    __shared__ __hip_bfloat16 As[128 * 64];
    __shared__ __hip_bfloat16 Bs[128 * 64];

    const int tid  = threadIdx.x;
    const int lane = tid & 63;
    const int wid  = tid >> 6;
    const int wr   = wid >> 1;        // wave row (0..1) -> 64 rows of C
    const int wc   = wid & 1;         // wave col (0..1) -> 64 cols of C
    const int fq   = lane >> 4;       // 0..3
    const int fr   = lane & 15;       // 0..15

    const int n0 = blockIdx.x * 128;  // col tile (gate-uniform: 128 | 1024)
    const int m0 = blockIdx.y * 128;

    const char* Abase = (const char*)(A  + (size_t)m0 * K_);
    const char* Bbase = (const char*)(Bm + (size_t)n0 * K_);

    // staging: 16 chunks of 1KB per tile; chunk = 8 rows x 128B.
    // lane l: row (l>>3), swizzled col slot ((l&7)^(l>>3))*16 B.
    const int srow  = lane >> 3;
    const int scolb = (((lane & 7) ^ (lane >> 3)) << 4);

    f32x4 acc[4][4] = {};

    for (int kt = 0; kt < K_ / 64; ++kt) {
        #pragma unroll
        for (int i = 0; i < 4; ++i) {
            const int chunk = i * 4 + wid;             // wave-uniform
            const int row   = chunk * 8 + srow;        // 0..127
            const char* srcA = Abase + (size_t)row * (K_ * 2) + kt * 128 + scolb;
            const char* srcB = Bbase + (size_t)row * (K_ * 2) + kt * 128 + scolb;
            __builtin_amdgcn_global_load_lds(
                (const __attribute__((address_space(1))) void*)srcA,
                (__attribute__((address_space(3))) void*)((char*)As + chunk * 1024),
                16, 0, 0);
            __builtin_amdgcn_global_load_lds(
                (const __attribute__((address_space(1))) void*)srcB,
                (__attribute__((address_space(3))) void*)((char*)Bs + chunk * 1024),
                16, 0, 0);
        }
        __syncthreads();

        #pragma unroll
        for (int ks = 0; ks < 2; ++ks) {
            bf16x8 af[4], bfr[4];
            #pragma unroll
            for (int m = 0; m < 4; ++m) {
                const int row = wr * 64 + m * 16 + fr;
                const int kb  = ks * 64 + fq * 16;     // byte offset in row
                af[m] = *(const bf16x8*)((const char*)As + row * 128 + (kb ^ ((row & 7) << 4)));
            }
            #pragma unroll
            for (int n = 0; n < 4; ++n) {
                const int row = wc * 64 + n * 16 + fr;
                const int kb  = ks * 64 + fq * 16;
                bfr[n] = *(const bf16x8*)((const char*)Bs + row * 128 + (kb ^ ((row & 7) << 4)));
            }
            #pragma unroll
            for (int m = 0; m < 4; ++m)
                #pragma unroll
                for (int n = 0; n < 4; ++n)
                    acc[m][n] = __builtin_amdgcn_mfma_f32_16x16x32_bf16(
                        af[m], bfr[n], acc[m][n], 0, 0, 0);
        }
        __syncthreads();
    }

    // ---- epilogue: bias + activation -> z/f/o plane (gate block-uniform) ---
    const int gate = n0 >> 10;                 // 0,1,2
    TO* buf = (gate == 0) ? zbuf : (gate == 1) ? fbuf : obuf;
    const int hbase = n0 & (H_ - 1);

    #pragma unroll
    for (int n = 0; n < 4; ++n) {
        const int col  = wc * 64 + n * 16 + fr;
        const float bv = bias[n0 + col];
        const int hcol = hbase + col;
        #pragma unroll
        for (int m = 0; m < 4; ++m) {
            #pragma unroll
            for (int j = 0; j < 4; ++j) {
                const int rowg = m0 + wr * 64 + m * 16 + fq * 4 + j;  // b*S+s
                const float v  = acc[m][n][j] + bv;
                float a;
                if (gate == 0) {
                    a = 2.f / (1.f + __expf(-2.f * v)) - 1.f;  // tanh
                } else {
                    a = 1.f / (1.f + __expf(-v));              // sigmoid
                }
                stv(buf, (size_t)rowg * H_ + hcol, a);
            }
        }
    }
}

// ---------------------------------------------------------------------------
// Sequential scan along S: one thread per (b,h).  c = f*c + (1-f)*z,
// out = o*c (f32), c_last appended after the [B,S,H] block.
// ---------------------------------------------------------------------------
template<typename TI>
__global__ __launch_bounds__(256) void qrnn_scan(
    const TI* __restrict__ zbuf,
    const TI* __restrict__ fbuf,
    const TI* __restrict__ obuf,
    const float* __restrict__ c0,
    float* __restrict__ out)
{
    const int t = blockIdx.x * 256 + threadIdx.x;   // 0 .. B*H-1
    const int b = t >> 10;
    const int h = t & (H_ - 1);

    float c = c0[t];                                // c0 is [B,H]
    const size_t base = (size_t)b * S_ * H_ + h;

    #pragma unroll 8
    for (int s = 0; s < S_; ++s) {
        const size_t idx = base + (size_t)s * H_;
        const float f = ldv(fbuf, idx);
        const float z = ldv(zbuf, idx);
        const float o = ldv(obuf, idx);
        c = f * c + (1.f - f) * z;
        out[idx] = o * c;
    }
    out[(size_t)B_ * S_ * H_ + t] = c;
}

extern "C" void kernel_launch(void* const* d_in, const int* in_sizes, int n_in,
                              void* d_out, int out_size, void* d_ws, size_t ws_size,
                              hipStream_t stream) {
    const float* x = (const float*)d_in[0];
    const float* h = (const float*)d_in[1];
    const float* W = (const float*)d_in[2];
    const float* b = (const float*)d_in[3];
    float* out = (float*)d_out;

    // workspace layout: xb [M_*K_ bf16] | Wb [N_*K_ bf16] | z|f|o planes
    char* ws = (char*)d_ws;
    __hip_bfloat16* xb = (__hip_bfloat16*)ws;
    __hip_bfloat16* Wb = xb + (size_t)M_ * K_;
    char* planes = (char*)(Wb + (size_t)N_ * K_);

    const size_t planeElems = (size_t)M_ * H_;
    const size_t headBytes  = ((size_t)M_ * K_ + (size_t)N_ * K_) * 2;
    const bool f32planes = ws_size >= headBytes + 3 * planeElems * 4;

    // convert x, W to bf16
    cvt_f32_bf16<<<(M_ * K_ / 8 + 255) / 256, 256, 0, stream>>>(x, xb, M_ * K_ / 8);
    cvt_f32_bf16<<<(N_ * K_ / 8 + 255) / 256, 256, 0, stream>>>(W, Wb, N_ * K_ / 8);

    dim3 gGrid(N_ / 128, M_ / 128);     // (24, 128)
    if (f32planes) {
        float* zbuf = (float*)planes;
        float* fbuf = zbuf + planeElems;
        float* obuf = fbuf + planeElems;
        qrnn_gemm_act<float><<<gGrid, 256, 0, stream>>>(xb, Wb, b, zbuf, fbuf, obuf);
        qrnn_scan<float><<<(B_ * H_) / 256, 256, 0, stream>>>(zbuf, fbuf, obuf, h, out);
    } else {
        __hip_bfloat16* zbuf = (__hip_bfloat16*)planes;
        __hip_bfloat16* fbuf = zbuf + planeElems;
        __hip_bfloat16* obuf = fbuf + planeElems;
        qrnn_gemm_act<__hip_bfloat16><<<gGrid, 256, 0, stream>>>(xb, Wb, b, zbuf, fbuf, obuf);
        qrnn_scan<__hip_bfloat16><<<(B_ * H_) / 256, 256, 0, stream>>>(zbuf, fbuf, obuf, h, out);
    }
}

// Round 3
// 161.477 us; speedup vs baseline: 1.1477x; 1.1477x over previous
//
#include <hip/hip_runtime.h>
#include <hip/hip_bf16.h>
#include <stdint.h>

typedef __attribute__((ext_vector_type(8))) short bf16x8;
typedef __attribute__((ext_vector_type(4))) float f32x4;

#define B_ 32
#define S_ 512
#define I_ 512
#define H_ 1024
#define M_ (B_*S_)      /* 16384 */
#define N_ (3*H_)       /* 3072  */
#define K_ I_           /* 512   */

// ---------------------------------------------------------------------------
// Merged f32 -> bf16 conversion for x and W. 8 elems/thread, 16B stores.
// ---------------------------------------------------------------------------
struct alignas(16) Bf8 { __hip_bfloat16 h[8]; };

__device__ inline void cvt8(const float* __restrict__ in, __hip_bfloat16* __restrict__ out, int t) {
    const float4* p = (const float4*)(in + (size_t)t * 8);
    const float4 a = p[0], b = p[1];
    Bf8 o;
    o.h[0] = __float2bfloat16(a.x); o.h[1] = __float2bfloat16(a.y);
    o.h[2] = __float2bfloat16(a.z); o.h[3] = __float2bfloat16(a.w);
    o.h[4] = __float2bfloat16(b.x); o.h[5] = __float2bfloat16(b.y);
    o.h[6] = __float2bfloat16(b.z); o.h[7] = __float2bfloat16(b.w);
    ((Bf8*)out)[t] = o;
}

__global__ __launch_bounds__(256) void cvt_xw(
    const float* __restrict__ x, __hip_bfloat16* __restrict__ xb, int n8x,
    const float* __restrict__ W, __hip_bfloat16* __restrict__ Wb, int n8w)
{
    const int t = blockIdx.x * 256 + threadIdx.x;
    if (t < n8x)                cvt8(x, xb, t);
    else if (t < n8x + n8w)     cvt8(W, Wb, t - n8x);
}

// ---------------------------------------------------------------------------
// GEMM + activation epilogue.
//   A  = xb [M_, K_] bf16 row-major (row = b*S+s); Bm = Wb [N_, K_] bf16.
//   y = A@Bm^T + bias; gate 0 -> tanh -> zbuf (bf16);
//   gate 1 -> sigmoid -> fbuf (f32); gate 2 -> sigmoid -> obuf (bf16).
// 128x128 tile, BK=64, 4 waves 2x2, mfma_f32_16x16x32_bf16,
// global_load_lds w16 + XOR swizzle (src cols + read addr, linear dest).
// Bijective XCD swizzle on the flattened 3072-block grid (3072 % 8 == 0).
// ---------------------------------------------------------------------------
__global__ __launch_bounds__(256) void qrnn_gemm_act(
    const __hip_bfloat16* __restrict__ A,
    const __hip_bfloat16* __restrict__ Bm,
    const float* __restrict__ bias,
    __hip_bfloat16* __restrict__ zbuf,
    float* __restrict__ fbuf,
    __hip_bfloat16* __restrict__ obuf)
{
    __shared__ __hip_bfloat16 As[128 * 64];
    __shared__ __hip_bfloat16 Bs[128 * 64];

    const int tid  = threadIdx.x;
    const int lane = tid & 63;
    const int wid  = tid >> 6;
    const int wr   = wid >> 1;
    const int wc   = wid & 1;
    const int fq   = lane >> 4;
    const int fr   = lane & 15;

    // XCD swizzle: 3072 blocks, 8 XCDs, 384 consecutive ids per XCD
    // (= 16 full row-panels of 24 column-tiles -> A read once per panel).
    const int id  = blockIdx.x;
    const int swz = (id & 7) * 384 + (id >> 3);
    const int bx  = swz % 24;          // column tile
    const int by  = swz / 24;          // row tile
    const int n0  = bx * 128;
    const int m0  = by * 128;

    const char* Abase = (const char*)(A  + (size_t)m0 * K_);
    const char* Bbase = (const char*)(Bm + (size_t)n0 * K_);

    const int srow  = lane >> 3;
    const int scolb = (((lane & 7) ^ (lane >> 3)) << 4);

    f32x4 acc[4][4] = {};

    for (int kt = 0; kt < K_ / 64; ++kt) {
        #pragma unroll
        for (int i = 0; i < 4; ++i) {
            const int chunk = i * 4 + wid;
            const int row   = chunk * 8 + srow;
            const char* srcA = Abase + (size_t)row * (K_ * 2) + kt * 128 + scolb;
            const char* srcB = Bbase + (size_t)row * (K_ * 2) + kt * 128 + scolb;
            __builtin_amdgcn_global_load_lds(
                (const __attribute__((address_space(1))) void*)srcA,
                (__attribute__((address_space(3))) void*)((char*)As + chunk * 1024),
                16, 0, 0);
            __builtin_amdgcn_global_load_lds(
                (const __attribute__((address_space(1))) void*)srcB,
                (__attribute__((address_space(3))) void*)((char*)Bs + chunk * 1024),
                16, 0, 0);
        }
        __syncthreads();

        #pragma unroll
        for (int ks = 0; ks < 2; ++ks) {
            bf16x8 af[4], bfr[4];
            #pragma unroll
            for (int m = 0; m < 4; ++m) {
                const int row = wr * 64 + m * 16 + fr;
                const int kb  = ks * 64 + fq * 16;
                af[m] = *(const bf16x8*)((const char*)As + row * 128 + (kb ^ ((row & 7) << 4)));
            }
            #pragma unroll
            for (int n = 0; n < 4; ++n) {
                const int row = wc * 64 + n * 16 + fr;
                const int kb  = ks * 64 + fq * 16;
                bfr[n] = *(const bf16x8*)((const char*)Bs + row * 128 + (kb ^ ((row & 7) << 4)));
            }
            #pragma unroll
            for (int m = 0; m < 4; ++m)
                #pragma unroll
                for (int n = 0; n < 4; ++n)
                    acc[m][n] = __builtin_amdgcn_mfma_f32_16x16x32_bf16(
                        af[m], bfr[n], acc[m][n], 0, 0, 0);
        }
        __syncthreads();
    }

    // ---- epilogue: bias + activation (gate block-uniform) ------------------
    const int gate  = n0 >> 10;                 // 0: z(tanh), 1: f(sig), 2: o(sig)
    const int hbase = n0 & (H_ - 1);

    #pragma unroll
    for (int n = 0; n < 4; ++n) {
        const int col  = wc * 64 + n * 16 + fr;
        const float bv = bias[n0 + col];
        const int hcol = hbase + col;
        #pragma unroll
        for (int m = 0; m < 4; ++m) {
            #pragma unroll
            for (int j = 0; j < 4; ++j) {
                const int rowg = m0 + wr * 64 + m * 16 + fq * 4 + j;  // b*S+s
                const float v  = acc[m][n][j] + bv;
                const size_t idx = (size_t)rowg * H_ + hcol;
                if (gate == 0) {
                    const float a = 2.f * __builtin_amdgcn_rcpf(1.f + __expf(-2.f * v)) - 1.f;
                    zbuf[idx] = __float2bfloat16(a);
                } else if (gate == 1) {
                    fbuf[idx] = __builtin_amdgcn_rcpf(1.f + __expf(-v));
                } else {
                    const float a = __builtin_amdgcn_rcpf(1.f + __expf(-v));
                    obuf[idx] = __float2bfloat16(a);
                }
            }
        }
    }
}

// ---------------------------------------------------------------------------
// Sequential scan along S: one thread per (b,h), 64-thread blocks so all
// 256 CUs are populated (512 waves).  c = f*c + (1-f)*z, out = o*c (f32),
// c_last appended after the [B,S,H] block.
// ---------------------------------------------------------------------------
__global__ __launch_bounds__(64) void qrnn_scan(
    const __hip_bfloat16* __restrict__ zbuf,
    const float* __restrict__ fbuf,
    const __hip_bfloat16* __restrict__ obuf,
    const float* __restrict__ c0,
    float* __restrict__ out)
{
    const int t = blockIdx.x * 64 + threadIdx.x;    // 0 .. B*H-1
    const int b = t >> 10;
    const int h = t & (H_ - 1);

    float c = c0[t];
    const size_t base = (size_t)b * S_ * H_ + h;

    #pragma unroll 8
    for (int s = 0; s < S_; ++s) {
        const size_t idx = base + (size_t)s * H_;
        const float f = fbuf[idx];
        const float z = __bfloat162float(zbuf[idx]);
        const float o = __bfloat162float(obuf[idx]);
        c = f * c + (1.f - f) * z;
        out[idx] = o * c;
    }
    out[(size_t)B_ * S_ * H_ + t] = c;
}

extern "C" void kernel_launch(void* const* d_in, const int* in_sizes, int n_in,
                              void* d_out, int out_size, void* d_ws, size_t ws_size,
                              hipStream_t stream) {
    const float* x = (const float*)d_in[0];
    const float* h = (const float*)d_in[1];
    const float* W = (const float*)d_in[2];
    const float* b = (const float*)d_in[3];
    float* out = (float*)d_out;

    // ws: xb [M_*K_ bf16] | Wb [N_*K_ bf16] | z bf16 | f f32 | o bf16
    char* ws = (char*)d_ws;
    __hip_bfloat16* xb = (__hip_bfloat16*)ws;
    __hip_bfloat16* Wb = xb + (size_t)M_ * K_;
    const size_t planeElems = (size_t)M_ * H_;
    __hip_bfloat16* zbuf = (__hip_bfloat16*)(Wb + (size_t)N_ * K_);
    float*          fbuf = (float*)(zbuf + planeElems);
    __hip_bfloat16* obuf = (__hip_bfloat16*)(fbuf + planeElems);

    const int n8x = M_ * K_ / 8, n8w = N_ * K_ / 8;
    cvt_xw<<<(n8x + n8w + 255) / 256, 256, 0, stream>>>(x, xb, n8x, W, Wb, n8w);

    qrnn_gemm_act<<<(N_ / 128) * (M_ / 128), 256, 0, stream>>>(xb, Wb, b, zbuf, fbuf, obuf);

    qrnn_scan<<<(B_ * H_) / 64, 64, 0, stream>>>(zbuf, fbuf, obuf, h, out);
}

// Round 4
// 129.976 us; speedup vs baseline: 1.4259x; 1.2424x over previous
//
#include <hip/hip_runtime.h>
#include <hip/hip_bf16.h>
#include <hip/hip_fp16.h>
#include <stdint.h>

typedef __attribute__((ext_vector_type(8))) _Float16 f16x8;
typedef __attribute__((ext_vector_type(4))) float f32x4;

#define B_  32
#define S_  512
#define K_  512
#define H_  1024
#define HS  128          // h-cols per block
#define SC  128          // s-rows per chunk
#define NKT 8            // K_/64
#define NSC 4            // S_/SC

// LDS layout (bytes): x-tile [128][64] f16 | W-tile [384][64] f16 | zf [2][128][130] f16
#define XS_OFF 0
#define WS_OFF 16384
#define ZF_OFF (16384 + 49152)
#define ZROW   260                      /* 130 f16: bank shift 1/row -> fq rows conflict-free */
#define LDS_BYTES (ZF_OFF + 2 * 128 * ZROW)   /* 132096 */

#define GLDS(src, dst) __builtin_amdgcn_global_load_lds( \
    (const __attribute__((address_space(1))) void*)(src), \
    (__attribute__((address_space(3))) void*)(dst), 16, 0, 0)

__device__ inline float sigm(float v) {
    return __builtin_amdgcn_rcpf(1.f + __expf(-v));
}

// ---------------------------------------------------------------------------
// f32 -> f16 conversion for x and W (f16: 8x less quant error than bf16,
// same MFMA rate). 8 elems/thread, 16B stores.
// ---------------------------------------------------------------------------
struct alignas(16) H8 { _Float16 h[8]; };

__global__ __launch_bounds__(256) void cvt_xw(
    const float* __restrict__ x, _Float16* __restrict__ xh, int n8x,
    const float* __restrict__ W, _Float16* __restrict__ Wh, int n8w)
{
    const int t = blockIdx.x * 256 + threadIdx.x;
    const float* src; _Float16* dst; int i;
    if (t < n8x)             { src = x; dst = xh; i = t; }
    else if (t < n8x + n8w)  { src = W; dst = Wh; i = t - n8x; }
    else return;
    const float4* p = (const float4*)(src + (size_t)i * 8);
    const float4 a = p[0], b = p[1];
    H8 o;
    o.h[0] = (_Float16)a.x; o.h[1] = (_Float16)a.y;
    o.h[2] = (_Float16)a.z; o.h[3] = (_Float16)a.w;
    o.h[4] = (_Float16)b.x; o.h[5] = (_Float16)b.y;
    o.h[6] = (_Float16)b.z; o.h[7] = (_Float16)b.w;
    ((H8*)dst)[i] = o;
}

// ---------------------------------------------------------------------------
// Fused GEMM + activations + scan + output. One block per (b, h-slice):
// 256 blocks (1/CU), 512 threads (8 waves: sw = wid>>2 in {0,1} splits s,
// gw = wid&3 splits the 384 gate-cols into 96-col strips).
// Per s-chunk (128 rows):
//   GEMM over K=512 (BK=64): stage x[128x64] + W[384x64] via global_load_lds
//   w16 (XOR-swizzled source cols, linear LDS dest, swizzled frag reads);
//   stage(kt+1) issued BEFORE MFMA(kt) so HBM/L2 latency hides under MFMA.
//   Epilogue: z=tanh, f=sigmoid -> zf LDS (f16, pad-130 rows).
//   Scan: threads 0..127 own one h-col each, c in f32 reg across chunks;
//   c written back into the z slot (f16).
//   Out: o-owning waves (gw>=2) apply sigmoid to their acc, multiply by c
//   from LDS, store f32 out directly.
// ---------------------------------------------------------------------------
__global__ __launch_bounds__(512, 2) void qrnn_fused(
    const _Float16* __restrict__ xh,   // [B*S, K]
    const _Float16* __restrict__ Wh,   // [3H, K]
    const float* __restrict__ bias,    // [3H]
    const float* __restrict__ c0,      // [B, H]
    float* __restrict__ out)           // [B,S,H] ++ [B,H]
{
    extern __shared__ char smem[];

    const int tid  = threadIdx.x;
    const int lane = tid & 63;
    const int wid  = tid >> 6;
    const int gw   = wid & 3;          // gate-col strip (96 cols)
    const int sw   = wid >> 2;         // s-half (64 rows)
    const int fq   = lane >> 4;
    const int fr   = lane & 15;

    const int b  = blockIdx.x & 31;    // XCD = bid%8 = b%8 -> x[b] L2-local
    const int hs = blockIdx.x >> 5;    // h-slice

    // bias per frag-col (constant across chunks)
    float bias_r[6];
    #pragma unroll
    for (int n = 0; n < 6; ++n) {
        const int g = gw * 96 + n * 16 + fr;
        bias_r[n] = bias[(g >> 7) * H_ + hs * HS + (g & 127)];
    }

    // recurrence state: thread t < 128 owns h-col t
    float c = 0.f;
    if (tid < HS) c = c0[b * H_ + hs * HS + tid];

    // staging lane constants (proven m97 pattern)
    const int srow  = lane >> 3;
    const int scolb = (((lane & 7) ^ (lane >> 3)) << 4);
    const _Float16* xbase = xh + (size_t)(b * S_) * K_;

    auto STAGE = [&](int sc_, int kt_) {
        #pragma unroll
        for (int i = 0; i < 8; ++i) {
            const int cid = wid * 8 + i;           // 0..63 chunks of 1KB
            if (cid < 16) {                        // x-tile: rows = s'
                const int r = cid * 8 + srow;
                const char* src = (const char*)(xbase + (size_t)(sc_ * SC + r) * K_ + kt_ * 64) + scolb;
                GLDS(src, smem + XS_OFF + cid * 1024);
            } else {                               // W-tile: rows = g 0..383
                const int r = (cid - 16) * 8 + srow;
                const int wrow = (r >> 7) * H_ + hs * HS + (r & 127);
                const char* src = (const char*)(Wh + (size_t)wrow * K_ + kt_ * 64) + scolb;
                GLDS(src, smem + WS_OFF + (cid - 16) * 1024);
            }
        }
    };

    STAGE(0, 0);
    __syncthreads();

    for (int sc = 0; sc < NSC; ++sc) {
        f32x4 acc[4][6] = {};

        for (int kt = 0; kt < NKT; ++kt) {
            f16x8 af[2][4], bf[2][6];
            #pragma unroll
            for (int ks = 0; ks < 2; ++ks) {
                #pragma unroll
                for (int m = 0; m < 4; ++m) {
                    const int row = sw * 64 + m * 16 + fr;
                    const int kb  = ks * 64 + fq * 16;
                    af[ks][m] = *(const f16x8*)(smem + XS_OFF + row * 128 + (kb ^ ((row & 7) << 4)));
                }
                #pragma unroll
                for (int n = 0; n < 6; ++n) {
                    const int row = gw * 96 + n * 16 + fr;
                    const int kb  = ks * 64 + fq * 16;
                    bf[ks][n] = *(const f16x8*)(smem + WS_OFF + row * 128 + (kb ^ ((row & 7) << 4)));
                }
            }
            __syncthreads();                        // all frag reads landed
            if (kt + 1 < NKT) STAGE(sc, kt + 1);    // async restage under MFMA
            __builtin_amdgcn_s_setprio(1);
            #pragma unroll
            for (int ks = 0; ks < 2; ++ks)
                #pragma unroll
                for (int m = 0; m < 4; ++m)
                    #pragma unroll
                    for (int n = 0; n < 6; ++n)
                        acc[m][n] = __builtin_amdgcn_mfma_f32_16x16x32_f16(
                            af[ks][m], bf[ks][n], acc[m][n], 0, 0, 0);
            __builtin_amdgcn_s_setprio(0);
            __syncthreads();                        // stage landed (vmcnt+lgkm drained)
        }

        // ---- epilogue: z (tanh), f (sigmoid) -> zf LDS ----------------------
        #pragma unroll
        for (int n = 0; n < 6; ++n) {
            const int g    = gw * 96 + n * 16 + fr;
            const int gate = g >> 7;                // wave-uniform per n
            if (gate == 2) continue;                // o stays in acc
            const int h = g & 127;
            #pragma unroll
            for (int m = 0; m < 4; ++m) {
                #pragma unroll
                for (int j = 0; j < 4; ++j) {
                    const int sl  = sw * 64 + m * 16 + fq * 4 + j;
                    const float v = acc[m][n][j] + bias_r[n];
                    const float a = (gate == 0)
                        ? 2.f * sigm(2.f * v) - 1.f   // tanh
                        : sigm(v);
                    *(_Float16*)(smem + ZF_OFF + gate * (128 * ZROW) + sl * ZROW + h * 2) = (_Float16)a;
                }
            }
        }
        __syncthreads();

        // ---- scan: 128 threads, one h-col each; c into z slot ---------------
        if (tid < HS) {
            #pragma unroll 4
            for (int s = 0; s < SC; ++s) {
                const float z = (float)*(const _Float16*)(smem + ZF_OFF + s * ZROW + tid * 2);
                const float f = (float)*(const _Float16*)(smem + ZF_OFF + 128 * ZROW + s * ZROW + tid * 2);
                c = __builtin_fmaf(f, c - z, z);     // f*c + (1-f)*z
                *(_Float16*)(smem + ZF_OFF + s * ZROW + tid * 2) = (_Float16)c;
            }
        }
        __syncthreads();

        if (sc + 1 < NSC) STAGE(sc + 1, 0);         // prefetch under out-phase

        // ---- out: o-owning waves multiply acc-sigmoid by c ------------------
        if (gw >= 2) {
            #pragma unroll
            for (int n = 0; n < 6; ++n) {
                const int g = gw * 96 + n * 16 + fr;
                if ((gw * 96 + n * 16) < 256) continue;   // gate 0/1 cols
                const int h = g - 256;
                #pragma unroll
                for (int m = 0; m < 4; ++m) {
                    #pragma unroll
                    for (int j = 0; j < 4; ++j) {
                        const int sl  = sw * 64 + m * 16 + fq * 4 + j;
                        const float o = sigm(acc[m][n][j] + bias_r[n]);
                        const float cc = (float)*(const _Float16*)(smem + ZF_OFF + sl * ZROW + h * 2);
                        out[(size_t)(b * S_ + sc * SC + sl) * H_ + hs * HS + h] = o * cc;
                    }
                }
            }
        }
        __syncthreads();                            // zf free + stage landed
    }

    // c_last tail: [1,B,H] appended after [B,S,H]
    if (tid < HS) out[(size_t)B_ * S_ * H_ + b * H_ + hs * HS + tid] = c;
}

extern "C" void kernel_launch(void* const* d_in, const int* in_sizes, int n_in,
                              void* d_out, int out_size, void* d_ws, size_t ws_size,
                              hipStream_t stream) {
    const float* x = (const float*)d_in[0];
    const float* h = (const float*)d_in[1];
    const float* W = (const float*)d_in[2];
    const float* b = (const float*)d_in[3];
    float* out = (float*)d_out;

    // ws: xh [B*S*K f16] | Wh [3H*K f16]
    _Float16* xh = (_Float16*)d_ws;
    _Float16* Wh = xh + (size_t)B_ * S_ * K_;

    // allow >64KB dynamic LDS (no-op if already set; not a stream op)
    static bool attr_set = false;
    if (!attr_set) {
        hipFuncSetAttribute((const void*)qrnn_fused,
                            hipFuncAttributeMaxDynamicSharedMemorySize, LDS_BYTES);
        attr_set = true;
    }

    const int n8x = B_ * S_ * K_ / 8;   // 1048576
    const int n8w = 3 * H_ * K_ / 8;    // 196608
    cvt_xw<<<(n8x + n8w + 255) / 256, 256, 0, stream>>>(x, xh, n8x, W, Wh, n8w);

    qrnn_fused<<<B_ * (H_ / HS), 512, LDS_BYTES, stream>>>(xh, Wh, b, h, out);
}

// Round 5
// 115.031 us; speedup vs baseline: 1.6112x; 1.1299x over previous
//
#include <hip/hip_runtime.h>
#include <hip/hip_bf16.h>
#include <hip/hip_fp16.h>
#include <stdint.h>

typedef __attribute__((ext_vector_type(8))) _Float16 f16x8;
typedef __attribute__((ext_vector_type(4))) float f32x4;

#define B_  32
#define S_  512
#define K_  512
#define H_  1024
#define HS  64           // h-cols per block
#define SC  128          // s-rows per chunk
#define NKT 8            // K_/64
#define NSC 4            // S_/SC

// LDS (bytes): x [128][64] f16 (16K) | W [192][64] f16 (24K) | zf [2][128] rows of 136B
// ZROWB=136 -> row stride 34 banks (~2 mod 8), so the epilogue/out fq-groups
// (4-row stride = 8 banks) tile all 32 banks conflict-free; scan row read
// (64 lanes x 2B = 128B) is 2 lanes/bank = free.
#define XS_OFF 0
#define WS_OFF 16384
#define ZF_OFF 40960
#define ZROWB  136
#define F_OFF  (ZF_OFF + 128 * ZROWB)
#define LDS_BYTES (ZF_OFF + 2 * 128 * ZROWB)   /* 75776: 2 blocks/CU */

#define GLDS(src, dst) __builtin_amdgcn_global_load_lds( \
    (const __attribute__((address_space(1))) void*)(src), \
    (__attribute__((address_space(3))) void*)(dst), 16, 0, 0)

__device__ inline float sigm(float v) {
    return __builtin_amdgcn_rcpf(1.f + __expf(-v));
}

// ---------------------------------------------------------------------------
// f32 -> f16 conversion for x and W. 8 elems/thread, 16B stores.
// ---------------------------------------------------------------------------
struct alignas(16) H8 { _Float16 h[8]; };

__global__ __launch_bounds__(256) void cvt_xw(
    const float* __restrict__ x, _Float16* __restrict__ xh, int n8x,
    const float* __restrict__ W, _Float16* __restrict__ Wh, int n8w)
{
    const int t = blockIdx.x * 256 + threadIdx.x;
    const float* src; _Float16* dst; int i;
    if (t < n8x)             { src = x; dst = xh; i = t; }
    else if (t < n8x + n8w)  { src = W; dst = Wh; i = t - n8x; }
    else return;
    const float4* p = (const float4*)(src + (size_t)i * 8);
    const float4 a = p[0], b = p[1];
    H8 o;
    o.h[0] = (_Float16)a.x; o.h[1] = (_Float16)a.y;
    o.h[2] = (_Float16)a.z; o.h[3] = (_Float16)a.w;
    o.h[4] = (_Float16)b.x; o.h[5] = (_Float16)b.y;
    o.h[6] = (_Float16)b.z; o.h[7] = (_Float16)b.w;
    ((H8*)dst)[i] = o;
}

// ---------------------------------------------------------------------------
// Fused GEMM + activations + scan + output.
// Grid: 512 blocks = (b, hs) with XCD-affine mapping (each XCD sees 4 b's ->
// x slice 2MB, L2-resident). Block: 256 threads = 4 waves (2 sw x 2 gw),
// per-wave tile 64 s-rows x 96 gate-cols, acc 4x6, mfma_f32_16x16x32_f16.
// 74KB LDS -> 2 blocks/CU: one block's epilogue/scan/out overlaps the
// other's MFMA K-loop.
// Per s-chunk (128 rows):
//   K-loop (BK=64): read frags -> barrier -> STAGE(kt+1) (glds w16, XOR
//   swizzle src+read, linear dest) -> setprio(1) MFMA -> barrier.
//   Epilogue: z=tanh, f=sigm -> zf LDS (f16, 136B rows). o stays in acc.
//   Scan: wave0's 64 lanes own one h-col each, c in f32 reg; c -> z slot.
//   Out: gate-2 waves sigm(acc)*c -> f32 out, STAGE(sc+1,0) hides under it.
// ---------------------------------------------------------------------------
__global__ __launch_bounds__(256, 2) void qrnn_fused(
    const _Float16* __restrict__ xh,   // [B*S, K]
    const _Float16* __restrict__ Wh,   // [3H, K]
    const float* __restrict__ bias,    // [3H]
    const float* __restrict__ c0,      // [B, H]
    float* __restrict__ out)           // [B,S,H] ++ [B,H]
{
    extern __shared__ char smem[];

    const int tid  = threadIdx.x;
    const int lane = tid & 63;
    const int wid  = tid >> 6;
    const int gw   = wid & 1;          // gate-col strip (96 cols)
    const int sw   = wid >> 1;         // s-half (64 rows)
    const int fq   = lane >> 4;
    const int fr   = lane & 15;

    // XCD-affine (b, hs): XCD = bid%8 sees b in {x, x+8, x+16, x+24}
    const int bid = blockIdx.x;
    const int b   = (bid & 7) + ((bid >> 7) << 3);
    const int hs  = (bid >> 3) & 15;

    // bias per frag-col (constant across chunks)
    float bias_r[6];
    #pragma unroll
    for (int n = 0; n < 6; ++n) {
        const int g = gw * 96 + n * 16 + fr;
        bias_r[n] = bias[(g >> 6) * H_ + hs * HS + (g & 63)];
    }

    // recurrence state: wave0 lane t owns h-col t
    float c = 0.f;
    if (tid < HS) c = c0[b * H_ + hs * HS + tid];

    const int srow  = lane >> 3;
    const int scolb = (((lane & 7) ^ (lane >> 3)) << 4);
    const _Float16* xbase = xh + (size_t)(b * S_) * K_;

    auto STAGE = [&](int sc_, int kt_) {
        #pragma unroll
        for (int i = 0; i < 10; ++i) {
            const int cid = wid * 10 + i;          // 0..39 chunks of 1KB
            if (cid < 16) {                        // x-tile rows (s')
                const int r = cid * 8 + srow;
                const char* src = (const char*)(xbase + (size_t)(sc_ * SC + r) * K_ + kt_ * 64) + scolb;
                GLDS(src, smem + XS_OFF + cid * 1024);
            } else {                               // W-tile rows (g 0..191)
                const int r = (cid - 16) * 8 + srow;
                const int wrow = (r >> 6) * H_ + hs * HS + (r & 63);
                const char* src = (const char*)(Wh + (size_t)wrow * K_ + kt_ * 64) + scolb;
                GLDS(src, smem + WS_OFF + (cid - 16) * 1024);
            }
        }
    };

    STAGE(0, 0);
    __syncthreads();

    for (int sc = 0; sc < NSC; ++sc) {
        f32x4 acc[4][6] = {};

        for (int kt = 0; kt < NKT; ++kt) {
            f16x8 af[2][4], bf[2][6];
            #pragma unroll
            for (int ks = 0; ks < 2; ++ks) {
                #pragma unroll
                for (int m = 0; m < 4; ++m) {
                    const int row = sw * 64 + m * 16 + fr;
                    const int kb  = ks * 64 + fq * 16;
                    af[ks][m] = *(const f16x8*)(smem + XS_OFF + row * 128 + (kb ^ ((row & 7) << 4)));
                }
                #pragma unroll
                for (int n = 0; n < 6; ++n) {
                    const int row = gw * 96 + n * 16 + fr;
                    const int kb  = ks * 64 + fq * 16;
                    bf[ks][n] = *(const f16x8*)(smem + WS_OFF + row * 128 + (kb ^ ((row & 7) << 4)));
                }
            }
            __syncthreads();                        // frag reads landed
            if (kt + 1 < NKT) STAGE(sc, kt + 1);    // restage under MFMA
            __builtin_amdgcn_s_setprio(1);
            #pragma unroll
            for (int ks = 0; ks < 2; ++ks)
                #pragma unroll
                for (int m = 0; m < 4; ++m)
                    #pragma unroll
                    for (int n = 0; n < 6; ++n)
                        acc[m][n] = __builtin_amdgcn_mfma_f32_16x16x32_f16(
                            af[ks][m], bf[ks][n], acc[m][n], 0, 0, 0);
            __builtin_amdgcn_s_setprio(0);
            __syncthreads();                        // stage landed
        }

        // ---- epilogue: z (tanh), f (sigmoid) -> zf LDS ----------------------
        #pragma unroll
        for (int n = 0; n < 6; ++n) {
            const int gbase = gw * 96 + n * 16;
            const int gate  = gbase >> 6;           // wave-uniform per n
            if (gate == 2) continue;                // o stays in acc
            const int h = (gbase + fr) & 63;
            #pragma unroll
            for (int m = 0; m < 4; ++m) {
                #pragma unroll
                for (int j = 0; j < 4; ++j) {
                    const int sl  = sw * 64 + m * 16 + fq * 4 + j;
                    const float v = acc[m][n][j] + bias_r[n];
                    const float a = (gate == 0)
                        ? 2.f * sigm(2.f * v) - 1.f   // tanh
                        : sigm(v);
                    *(_Float16*)(smem + ZF_OFF + gate * (128 * ZROWB) + sl * ZROWB + h * 2) = (_Float16)a;
                }
            }
        }
        __syncthreads();

        // ---- scan: wave0, one h-col per lane; c back into z slot ------------
        if (tid < HS) {
            #pragma unroll 8
            for (int s = 0; s < SC; ++s) {
                const float z = (float)*(const _Float16*)(smem + ZF_OFF + s * ZROWB + tid * 2);
                const float f = (float)*(const _Float16*)(smem + F_OFF  + s * ZROWB + tid * 2);
                c = __builtin_fmaf(f, c - z, z);     // f*c + (1-f)*z
                *(_Float16*)(smem + ZF_OFF + s * ZROWB + tid * 2) = (_Float16)c;
            }
        }
        __syncthreads();

        if (sc + 1 < NSC) STAGE(sc + 1, 0);         // prefetch under out-phase

        // ---- out: gate-2 cols: sigm(acc)*c -> f32 out -----------------------
        #pragma unroll
        for (int n = 0; n < 6; ++n) {
            const int gbase = gw * 96 + n * 16;
            if ((gbase >> 6) != 2) continue;
            const int h = (gbase + fr) & 63;
            #pragma unroll
            for (int m = 0; m < 4; ++m) {
                #pragma unroll
                for (int j = 0; j < 4; ++j) {
                    const int sl  = sw * 64 + m * 16 + fq * 4 + j;
                    const float o = sigm(acc[m][n][j] + bias_r[n]);
                    const float cc = (float)*(const _Float16*)(smem + ZF_OFF + sl * ZROWB + h * 2);
                    out[(size_t)(b * S_ + sc * SC + sl) * H_ + hs * HS + h] = o * cc;
                }
            }
        }
        __syncthreads();                            // zf free + stage landed
    }

    // c_last tail: [1,B,H] appended after [B,S,H]
    if (tid < HS) out[(size_t)B_ * S_ * H_ + b * H_ + hs * HS + tid] = c;
}

extern "C" void kernel_launch(void* const* d_in, const int* in_sizes, int n_in,
                              void* d_out, int out_size, void* d_ws, size_t ws_size,
                              hipStream_t stream) {
    const float* x = (const float*)d_in[0];
    const float* h = (const float*)d_in[1];
    const float* W = (const float*)d_in[2];
    const float* b = (const float*)d_in[3];
    float* out = (float*)d_out;

    // ws: xh [B*S*K f16] | Wh [3H*K f16]
    _Float16* xh = (_Float16*)d_ws;
    _Float16* Wh = xh + (size_t)B_ * S_ * K_;

    hipFuncSetAttribute((const void*)qrnn_fused,
                        hipFuncAttributeMaxDynamicSharedMemorySize, LDS_BYTES);

    const int n8x = B_ * S_ * K_ / 8;   // 1048576
    const int n8w = 3 * H_ * K_ / 8;    // 196608
    cvt_xw<<<(n8x + n8w + 255) / 256, 256, 0, stream>>>(x, xh, n8x, W, Wh, n8w);

    qrnn_fused<<<B_ * (H_ / HS), 256, LDS_BYTES, stream>>>(xh, Wh, b, h, out);
}